// Round 7
// baseline (289.518 us; speedup 1.0000x reference)
//
#include <hip/hip_runtime.h>

#define B_   8
#define T_   4096
#define D_   1024
#define E_   100
#define EP_  128
#define NTOK (B_*T_)
#define TC_  8            // t-chunks in k_feat
#define KT_  (T_/TC_)     // 512

typedef short bf16x8 __attribute__((ext_vector_type(8)));
typedef float f32x4  __attribute__((ext_vector_type(4)));

__device__ __forceinline__ unsigned short f2b(float f){
    union { float f; unsigned int i; } v; v.f = f;
    unsigned int x = v.i;
    return (unsigned short)((x + 0x7fffu + ((x >> 16) & 1u)) >> 16);
}
__device__ __forceinline__ uint4 pack8(float4 a, float4 b){
    uint4 r;
    r.x = (unsigned int)f2b(a.x) | ((unsigned int)f2b(a.y) << 16);
    r.y = (unsigned int)f2b(a.z) | ((unsigned int)f2b(a.w) << 16);
    r.z = (unsigned int)f2b(b.x) | ((unsigned int)f2b(b.y) << 16);
    r.w = (unsigned int)f2b(b.z) | ((unsigned int)f2b(b.w) << 16);
    return r;
}
__device__ __forceinline__ bf16x8 pk(float4 a, float4 b){
    union { uint4 u; bf16x8 h; } c; c.u = pack8(a, b); return c.h;
}
__device__ __forceinline__ void dma16(const unsigned short* g, unsigned short* l){
    __builtin_amdgcn_global_load_lds(
        (const __attribute__((address_space(1))) unsigned int*)(const void*)g,
        (__attribute__((address_space(3))) unsigned int*)(void*)l,
        16, 0, 0);
}

// ---------------- K1: normalize centroids (fp32 in) -> cn[EP_][D_] bf16 --------
__global__ __launch_bounds__(256) void k_cnorm(const float* __restrict__ cent,
                                               unsigned short* __restrict__ cn){
    const int e = blockIdx.x, tid = threadIdx.x;
    if (e >= E_){
        ((uint2*)(cn + (size_t)e*D_))[tid] = make_uint2(0u, 0u);
        return;
    }
    float4 x = ((const float4*)(cent + (size_t)e*D_))[tid];
    float ss = x.x*x.x + x.y*x.y + x.z*x.z + x.w*x.w;
    __shared__ float red[256];
    red[tid] = ss; __syncthreads();
    for (int s = 128; s > 0; s >>= 1){ if (tid < s) red[tid] += red[tid+s]; __syncthreads(); }
    float inv = 1.0f / fmaxf(sqrtf(red[0]), 1e-12f);
    unsigned int lo = (unsigned int)f2b(x.x*inv) | ((unsigned int)f2b(x.y*inv) << 16);
    unsigned int hi = (unsigned int)f2b(x.z*inv) | ((unsigned int)f2b(x.w*inv) << 16);
    ((uint2*)(cn + (size_t)e*D_))[tid] = make_uint2(lo, hi);
}

// ---------------- K2: max-ILP fused prep + sim GEMM + softmax ------------------
// grid = NTOK/16 = 2048 blocks x 512 thr (8 waves). Block = 16 tokens x 128 e.
// Wave w owns K-eighth [w*128, w*128+128): ALL loads (8 A-float4 + 32 B-bf16x8,
// ~160 VGPR of data) issued straight-line with no loop/LDS/barrier, then one
// wait region and 32 MFMAs. launch_bounds(512,2) allows ~256 VGPR/wave.
// Epilogue: padded-LDS K-combine + wave-parallel softmax + coalesced outputs.
__global__ __launch_bounds__(512, 2) void k_sim(const float* __restrict__ tokens,
                                                const unsigned short* __restrict__ cn,
                                                float* __restrict__ out_assign,
                                                unsigned short* __restrict__ pT,
                                                float* __restrict__ wpart){
    __shared__ __align__(16) char smem[78336];
    float* simp = (float*)smem;                           // [8][16][132] f32 (67584B, padded)
    unsigned short* spTp = (unsigned short*)(smem + 67584); // [128][24] bf16 (6144B)
    float* ssL  = (float*)(smem + 73728);                 // [8][16] (512B)
    float* watc = (float*)(smem + 74240);                 // [8][128] (4096B)

    const int tid  = threadIdx.x;
    const int w    = tid >> 6;           // 0..7 = K-eighth
    const int lane = tid & 63;
    const int lrow = lane & 15, quad = lane >> 4;

    const int t0  = blockIdx.x * 16;
    const int bb  = t0 >> 12;
    const int tl0 = t0 & (T_ - 1);

    // ---- straight-line GEMM over this wave's K-eighth ----
    const float* gA = tokens + (size_t)(t0 + lrow)*D_ + w*128 + quad*8;

    float4 Av[8];
    #pragma unroll
    for (int ks = 0; ks < 4; ks++){
        Av[2*ks]   = *(const float4*)(gA + ks*32);
        Av[2*ks+1] = *(const float4*)(gA + ks*32 + 4);
    }
    bf16x8 Bv[8][4];
    #pragma unroll
    for (int ni = 0; ni < 8; ni++){
        const unsigned short* gB = cn + (size_t)(ni*16 + lrow)*D_ + w*128 + quad*8;
        #pragma unroll
        for (int ks = 0; ks < 4; ks++)
            Bv[ni][ks] = *(const bf16x8*)(gB + ks*32);
    }

    float ss = 0.f;
    bf16x8 af[4];
    #pragma unroll
    for (int ks = 0; ks < 4; ks++){
        float4 a0 = Av[2*ks], a1 = Av[2*ks+1];
        ss += a0.x*a0.x + a0.y*a0.y + a0.z*a0.z + a0.w*a0.w
            + a1.x*a1.x + a1.y*a1.y + a1.z*a1.z + a1.w*a1.w;
        af[ks] = pk(a0, a1);
    }

    f32x4 acc[8];
    #pragma unroll
    for (int ni = 0; ni < 8; ni++) acc[ni] = (f32x4){0.f,0.f,0.f,0.f};
    __builtin_amdgcn_s_setprio(1);
    #pragma unroll
    for (int ks = 0; ks < 4; ks++)
        #pragma unroll
        for (int ni = 0; ni < 8; ni++)
            acc[ni] = __builtin_amdgcn_mfma_f32_16x16x32_bf16(af[ks], Bv[ni][ks], acc[ni], 0, 0, 0);
    __builtin_amdgcn_s_setprio(0);

    // ---- epilogue: combine 8 K-eighths ----
    ss += __shfl_xor(ss, 16);
    ss += __shfl_xor(ss, 32);
    if (quad == 0) ssL[w*16 + lrow] = ss;

    #pragma unroll
    for (int ni = 0; ni < 8; ni++){
        #pragma unroll
        for (int rr = 0; rr < 4; rr++){
            const int row = quad*4 + rr;
            simp[(w*16 + row)*132 + ni*16 + lrow] = acc[ni][rr];
        }
    }
    __syncthreads();

    // wave w handles rows 2w, 2w+1; lane covers cols lane, lane+64
    float wp0 = 0.f, wp1 = 0.f;
    #pragma unroll
    for (int rr = 0; rr < 2; rr++){
        const int r = 2*w + rr;
        float nsq = 0.f;
        #pragma unroll
        for (int q = 0; q < 8; q++) nsq += ssL[q*16 + r];
        const float sc = 10.0f / fmaxf(sqrtf(nsq), 1e-12f);
        const int c0 = lane, c1 = lane + 64;
        float v0 = 0.f, v1 = 0.f;
        #pragma unroll
        for (int q = 0; q < 8; q++){
            v0 += simp[(q*16 + r)*132 + c0];
            v1 += simp[(q*16 + r)*132 + c1];
        }
        v0 *= sc; v1 *= sc;
        float m = v0;                          // c0 < 64 < E_ always valid
        if (c1 < E_) m = fmaxf(m, v1);
        #pragma unroll
        for (int off = 1; off < 64; off <<= 1) m = fmaxf(m, __shfl_xor(m, off));
        float e0 = __expf(v0 - m);
        float e1 = (c1 < E_) ? __expf(v1 - m) : 0.f;
        float sum = e0 + e1;
        #pragma unroll
        for (int off = 1; off < 64; off <<= 1) sum += __shfl_xor(sum, off);
        const float rinv = 1.0f / sum;
        const float p0 = e0 * rinv;
        const float p1 = e1 * rinv;
        out_assign[(size_t)(t0 + r)*E_ + c0] = p0;          // coalesced 256B
        if (c1 < E_) out_assign[(size_t)(t0 + r)*E_ + c1] = p1;
        wp0 += p0; wp1 += p1;
        spTp[c0*24 + r] = f2b(p0);
        spTp[c1*24 + r] = f2b(p1);
    }
    watc[w*128 + lane]      = wp0;
    watc[w*128 + 64 + lane] = wp1;
    __syncthreads();

    if (tid < 128){
        float s = 0.f;
        #pragma unroll
        for (int q = 0; q < 8; q++) s += watc[q*128 + tid];
        wpart[((size_t)bb*256 + (tl0 >> 4))*EP_ + tid] = s;
    }
    // pT store: 256 threads -> (e = tid>>1, 8-half piece)
    if (tid < 256){
        const int e = tid >> 1;
        const int o = (tid & 1) * 8;
        uint4 v = *(const uint4*)(spTp + e*24 + o);
        *(uint4*)(pT + ((size_t)bb*EP_ + e)*T_ + tl0 + o) = v;
    }
}

// ---------------- K3: partial entity_features (r5 version: 128e x 64d) ---------
// grid = (16 d-tiles, TC_ t-chunks, 8 batches) = 1024 blocks. Dbuf, 1 barrier.
__global__ __launch_bounds__(256) void k_feat(const float* __restrict__ tokens,
                                              const unsigned short* __restrict__ pT,
                                              float* __restrict__ facc_part){
    const int tid = threadIdx.x;
    const int d0  = blockIdx.x * 64;
    const int tc  = blockIdx.y;
    const int bb  = blockIdx.z;

    __shared__ __align__(16) unsigned short lds_a[2][128*64];   // 2 x 16KB  [e][t]
    __shared__ __align__(16) unsigned short lds_b[2][64*64];    // 2 x 8KB   [d][t]

    const int lane = tid & 63, w = tid >> 6;
    const int wm = w >> 1, wn = w & 1, lrow = lane & 15, quad = lane >> 4;

    // A DMA: wave w fills chunks c=4w..4w+3 (rows 8c..8c+7), swizzled source.
    const unsigned short* gA[4];
    int lAoff[4];
    #pragma unroll
    for (int j = 0; j < 4; j++){
        int c = 4*w + j;
        int brow = 8*c + (lane >> 3);
        int bjg  = (lane & 7) ^ (brow & 7);
        gA[j] = pT + ((size_t)bb*EP_ + brow)*T_ + tc*KT_ + bjg*8;
        lAoff[j] = c*512;
    }

    // B: thread owns d-column dcol (0..63) and t-octets o1, o1+4.
    const int dcol = tid & 63;
    const int o1 = tid >> 6;            // 0..3
    const float* gB = tokens + ((size_t)bb*T_ + (size_t)tc*KT_)*D_ + d0 + dcol;
    const int s1 = o1 ^ (dcol & 7), s2 = (o1 + 4) ^ (dcol & 7);
    const int b1off = dcol*64 + s1*8;
    const int b2off = dcol*64 + s2*8;

    f32x4 acc[4][2];
    #pragma unroll
    for (int i = 0; i < 4; i++)
        #pragma unroll
        for (int j = 0; j < 2; j++) acc[i][j] = (f32x4){0.f,0.f,0.f,0.f};

    // prologue: chunk 0 (B raw loads first -> oldest in vmcnt FIFO)
    float b1[8], b2[8];
    #pragma unroll
    for (int tt = 0; tt < 8; tt++) b1[tt] = gB[(size_t)(o1*8 + tt)*D_];
    #pragma unroll
    for (int tt = 0; tt < 8; tt++) b2[tt] = gB[(size_t)((o1+4)*8 + tt)*D_];
    #pragma unroll
    for (int j = 0; j < 4; j++) dma16(gA[j], &lds_a[0][lAoff[j]]);
    *(uint4*)(&lds_b[0][b1off]) = pack8(make_float4(b1[0],b1[1],b1[2],b1[3]),
                                        make_float4(b1[4],b1[5],b1[6],b1[7]));
    *(uint4*)(&lds_b[0][b2off]) = pack8(make_float4(b2[0],b2[1],b2[2],b2[3]),
                                        make_float4(b2[4],b2[5],b2[6],b2[7]));

    for (int ki = 0; ki < 8; ki++){
        const int cur = ki & 1;
        __syncthreads();                       // buffers[cur] ready (vmcnt+lgkm+bar)
        if (ki < 7){
            const int kt0 = (ki + 1) * 64;
            #pragma unroll
            for (int tt = 0; tt < 8; tt++) b1[tt] = gB[(size_t)(kt0 + o1*8 + tt)*D_];
            #pragma unroll
            for (int tt = 0; tt < 8; tt++) b2[tt] = gB[(size_t)(kt0 + (o1+4)*8 + tt)*D_];
            #pragma unroll
            for (int j = 0; j < 4; j++) dma16(gA[j] + kt0, &lds_a[1-cur][lAoff[j]]);
        }
        const unsigned short* aC = &lds_a[cur][0];
        const unsigned short* bC = &lds_b[cur][0];
        #pragma unroll
        for (int kk = 0; kk < 2; kk++){
            const int b = quad + 4*kk;
            bf16x8 af[4], bfr[2];
            #pragma unroll
            for (int mi = 0; mi < 4; mi++){
                const int e = wm*64 + mi*16 + lrow;
                af[mi] = *(const bf16x8*)(aC + e*64 + ((b ^ (e & 7)) * 8));
            }
            #pragma unroll
            for (int ni = 0; ni < 2; ni++){
                const int d = wn*32 + ni*16 + lrow;
                bfr[ni] = *(const bf16x8*)(bC + d*64 + ((b ^ (d & 7)) * 8));
            }
            #pragma unroll
            for (int mi = 0; mi < 4; mi++)
                #pragma unroll
                for (int ni = 0; ni < 2; ni++)
                    acc[mi][ni] = __builtin_amdgcn_mfma_f32_16x16x32_bf16(af[mi], bfr[ni], acc[mi][ni], 0, 0, 0);
        }
        if (ki < 7){
            *(uint4*)(&lds_b[1-cur][b1off]) = pack8(make_float4(b1[0],b1[1],b1[2],b1[3]),
                                                    make_float4(b1[4],b1[5],b1[6],b1[7]));
            *(uint4*)(&lds_b[1-cur][b2off]) = pack8(make_float4(b2[0],b2[1],b2[2],b2[3]),
                                                    make_float4(b2[4],b2[5],b2[6],b2[7]));
        }
    }

    #pragma unroll
    for (int mi = 0; mi < 4; mi++){
        #pragma unroll
        for (int ni = 0; ni < 2; ni++){
            int d = d0 + wn*32 + ni*16 + lrow;
            #pragma unroll
            for (int rr = 0; rr < 4; rr++){
                int e = wm*64 + mi*16 + quad*4 + rr;
                if (e < E_)
                    facc_part[((size_t)(tc*B_ + bb)*E_ + e)*D_ + d] = acc[mi][ni][rr];
            }
        }
    }
}

// ---------------- K4: w = sum chunks; out = (sum parts)/(w+eps) ----------------
// grid = (E_, B_), 256 threads. wpart has 256 chunks of 16 tokens.
__global__ __launch_bounds__(256) void k_final(const float* __restrict__ wpart,
                                               const float* __restrict__ facc_part,
                                               float* __restrict__ out_feat){
    const int e  = blockIdx.x;
    const int bb = blockIdx.y;
    const int tid = threadIdx.x;

    __shared__ float red[256];
    red[tid] = wpart[((size_t)bb*256 + tid)*EP_ + e];
    __syncthreads();
    for (int st = 128; st > 0; st >>= 1){ if (tid < st) red[tid] += red[tid+st]; __syncthreads(); }
    const float winv = 1.0f / (red[0] + 1e-6f);

    const int d = tid * 4;
    float4 o = make_float4(0.f, 0.f, 0.f, 0.f);
    #pragma unroll
    for (int tc = 0; tc < TC_; tc++){
        float4 p = *(const float4*)(facc_part + ((size_t)(tc*B_ + bb)*E_ + e)*D_ + d);
        o.x += p.x; o.y += p.y; o.z += p.z; o.w += p.w;
    }
    o.x *= winv; o.y *= winv; o.z *= winv; o.w *= winv;
    *(float4*)(out_feat + ((size_t)bb*E_ + e)*D_ + d) = o;
}

extern "C" void kernel_launch(void* const* d_in, const int* in_sizes, int n_in,
                              void* d_out, int out_size, void* d_ws, size_t ws_size,
                              hipStream_t stream){
    const float* tokens = (const float*)d_in[0];
    const float* cent   = (const float*)d_in[1];
    float* out        = (float*)d_out;
    float* out_assign = out;
    float* out_feat   = out + (size_t)B_*T_*E_;

    float* wpart = (float*)d_ws;                                      // B*256*128 f32
    float* facc_part = wpart + (size_t)B_*256*EP_;                    // TC_*B*E*D f32
    unsigned short* cn = (unsigned short*)(facc_part + (size_t)TC_*B_*E_*D_);  // EP_*D_ bf16
    unsigned short* pT = cn + (size_t)EP_*D_;                         // B_*EP_*T_ bf16

    k_cnorm<<<EP_, 256, 0, stream>>>(cent, cn);
    k_sim  <<<NTOK/16, 512, 0, stream>>>(tokens, cn, out_assign, pT, wpart);
    k_feat <<<dim3(16, TC_, B_), 256, 0, stream>>>(tokens, pT, facc_part);
    k_final<<<dim3(E_, B_), 256, 0, stream>>>(wpart, facc_part, out_feat);
}